// Round 7
// baseline (201.545 us; speedup 1.0000x reference)
//
#include <hip/hip_runtime.h>
#include <hip/hip_bf16.h>
#include <math.h>

#define T_TOK 8192
#define D_MODEL 2048
#define N_EXP 16
#define CAP 512
#define NSEG (T_TOK / 64)           // 128

// ws layout (bytes):
// aff:   0       .. 524288    float[T_TOK][16]
// pref:  524288  .. +65536    u64[T_TOK]
// probs: 589824  .. +524288   float[T_TOK][16]
// evt:   1114112 .. +128      int[32] (evp[16], evf[16])
// t2e:   1114240 .. +8192     u8[T_TOK]
// bcnt:  1122432 .. +2048     int[32][16]

__device__ __forceinline__ unsigned int f2ord(float f) {
    unsigned int b = __float_as_uint(f);
    return (b & 0x80000000u) ? ~b : (b | 0x80000000u);
}

// ---------------- Kernel 1: GEMM, W K-chunks double-buffered in LDS ----------------
// 512 blocks x 256 thr (4 waves); wave owns 4 tokens; lane slices K (4 floats/block).
// LDS 32 KB -> 4 blocks/CU by LDS; grid gives 2 blocks/CU (8 waves/CU).
__global__ __launch_bounds__(256, 2) void gemm_aff_kernel(
    const float* __restrict__ feat, const float* __restrict__ W,
    float* __restrict__ aff)
{
    __shared__ float w_lds[2][N_EXP][256];   // 2 x 16 KB

    const int tid  = threadIdx.x;
    const int wave = tid >> 6, lane = tid & 63;
    const int tbase = blockIdx.x * 16 + wave * 4;

    // staging: thread covers float4 slots q*256+tid (q=0..3): expert q*4+se, col sc4
    const int se  = tid >> 6;
    const int sc4 = tid & 63;

    const float* fbase = feat + (size_t)tbase * D_MODEL + lane * 4;

    float acc[64];   // acc[r*16+e]
    #pragma unroll
    for (int i = 0; i < 64; ++i) acc[i] = 0.f;

    float4 wreg[4];
    // chunk 0 -> LDS buf 0
    #pragma unroll
    for (int q = 0; q < 4; ++q)
        wreg[q] = *(const float4*)(W + (size_t)(q * 4 + se) * D_MODEL + sc4 * 4);
    #pragma unroll
    for (int q = 0; q < 4; ++q)
        *(float4*)&w_lds[0][q * 4 + se][sc4 * 4] = wreg[q];
    // chunk 1 -> regs (in flight)
    #pragma unroll
    for (int q = 0; q < 4; ++q)
        wreg[q] = *(const float4*)(W + (size_t)(q * 4 + se) * D_MODEL + 256 + sc4 * 4);

    float4 cur[4], nxt[4];
    #pragma unroll
    for (int r = 0; r < 4; ++r)
        cur[r] = *(const float4*)(fbase + (size_t)r * D_MODEL);

    __syncthreads();

    #pragma unroll
    for (int j = 0; j < 8; ++j) {           // 8 K-blocks of 256 floats
        const int buf = j & 1;
        if (j < 7) {
            #pragma unroll
            for (int r = 0; r < 4; ++r)
                nxt[r] = *(const float4*)(fbase + (size_t)r * D_MODEL + (j + 1) * 256);
        }
        #pragma unroll
        for (int e = 0; e < N_EXP; ++e) {
            float4 wv = *(const float4*)&w_lds[buf][e][lane * 4];
            #pragma unroll
            for (int r = 0; r < 4; ++r) {
                acc[r * 16 + e] += cur[r].x * wv.x;
                acc[r * 16 + e] += cur[r].y * wv.y;
                acc[r * 16 + e] += cur[r].z * wv.z;
                acc[r * 16 + e] += cur[r].w * wv.w;
            }
        }
        if (j < 7) {
            // store prefetched chunk j+1 into the other buffer
            #pragma unroll
            for (int q = 0; q < 4; ++q)
                *(float4*)&w_lds[buf ^ 1][q * 4 + se][sc4 * 4] = wreg[q];
            if (j < 6) {
                #pragma unroll
                for (int q = 0; q < 4; ++q)
                    wreg[q] = *(const float4*)(W + (size_t)(q * 4 + se) * D_MODEL + (j + 2) * 256 + sc4 * 4);
            }
        }
        __syncthreads();
        #pragma unroll
        for (int r = 0; r < 4; ++r) cur[r] = nxt[r];
    }

    // halving butterfly: 64 slots -> 1 slot/lane (verified r4-r6)
    #pragma unroll
    for (int step = 0; step < 6; ++step) {
        const int m    = 1 << step;
        const int half = 64 >> (step + 1);
        const bool hi  = (lane & m) != 0;
        #pragma unroll
        for (int jj = 0; jj < half; ++jj) {
            float send = hi ? acc[jj] : acc[jj + half];
            float recv = __shfl_xor(send, m, 64);
            acc[jj] = (hi ? acc[jj + half] : acc[jj]) + recv;
        }
    }
    const int slot = ((lane & 1) << 5) | (((lane >> 1) & 1) << 4) | (((lane >> 2) & 1) << 3)
                   | (((lane >> 3) & 1) << 2) | (((lane >> 4) & 1) << 1) | ((lane >> 5) & 1);
    const int r = slot >> 4, e = slot & 15;
    aff[(size_t)(tbase + r) * N_EXP + e] = acc[0];
}

// ---------------- Kernel 2: bias + softmax + preference lists ----------------
__global__ __launch_bounds__(256) void finalize_kernel(
    const float* __restrict__ aff_in, const float* __restrict__ bias,
    unsigned long long* __restrict__ pref, float* __restrict__ probs)
{
    const int t = blockIdx.x * 256 + threadIdx.x;

    float aff[N_EXP];
    const float4* p = (const float4*)(aff_in + (size_t)t * N_EXP);
    #pragma unroll
    for (int q = 0; q < 4; ++q) {
        float4 v = p[q];
        aff[q*4+0] = v.x; aff[q*4+1] = v.y; aff[q*4+2] = v.z; aff[q*4+3] = v.w;
    }
    #pragma unroll
    for (int e = 0; e < N_EXP; ++e) aff[e] += bias[e];

    float m = aff[0];
    #pragma unroll
    for (int e = 1; e < N_EXP; ++e) m = fmaxf(m, aff[e]);
    float s = 0.f;
    #pragma unroll
    for (int e = 0; e < N_EXP; ++e) s += __expf(aff[e] - m);

    float4* pr = (float4*)(probs + (size_t)t * N_EXP);
    #pragma unroll
    for (int q = 0; q < 4; ++q) {
        float4 v;
        v.x = __expf(aff[q*4+0] - m) / s;
        v.y = __expf(aff[q*4+1] - m) / s;
        v.z = __expf(aff[q*4+2] - m) / s;
        v.w = __expf(aff[q*4+3] - m) / s;
        pr[q] = v;
    }

    unsigned long long key[N_EXP];
    #pragma unroll
    for (int j = 0; j < N_EXP; ++j)
        key[j] = ((unsigned long long)f2ord(aff[j]) << 4) | (unsigned long long)(15 - j);
    unsigned long long pk = 0ull;
    unsigned int used = 0;
    for (int r = 0; r < N_EXP; ++r) {
        unsigned long long bk = 0ull; int be = 0;
        for (int j = 0; j < N_EXP; ++j)
            if (!((used >> j) & 1u) && key[j] > bk) { bk = key[j]; be = j; }
        used |= (1u << be);
        pk = (pk << 4) | (unsigned long long)be;
    }
    pref[t] = pk;
}

// ---------------- Kernel 3: fill-event schedule via segment bitmasks (1 block) ----------------
__global__ __launch_bounds__(512) void events_kernel(
    const unsigned long long* __restrict__ pref, int* __restrict__ evt)
{
    __shared__ unsigned long long prefL[T_TOK];            // 64 KB
    __shared__ unsigned long long segmask[N_EXP][NSEG + 1];// [e][s]
    __shared__ int pseg[N_EXP][NSEG + 1];
    __shared__ int rem_cap[N_EXP], fparr[N_EXP];
    __shared__ int s_avail, s_pmin, s_fe, s_seglo;
    __shared__ int evp[N_EXP], evf[N_EXP];

    const int tid  = threadIdx.x;
    const int wave = tid >> 6, lane = tid & 63;
    const unsigned long long lt_mask = (1ull << lane) - 1ull;

    for (int i = tid; i < T_TOK; i += 512) prefL[i] = pref[i];
    if (tid < N_EXP) rem_cap[tid] = CAP;
    if (tid == 0) { s_avail = 0xFFFF; s_seglo = 0; }
    __syncthreads();

    // initial masks from top-nibble choice
    for (int s = wave; s < NSEG; s += 8) {
        int c = (int)(prefL[s * 64 + lane] >> 60);
        #pragma unroll
        for (int e = 0; e < N_EXP; ++e) {
            unsigned long long mm = __ballot(c == e);
            if (lane == e) segmask[e][s] = mm;
        }
    }
    __syncthreads();

    for (int round = 0; round < N_EXP; ++round) {
        const unsigned int avail = (unsigned int)s_avail;

        // A: counts from popc, prefix scan, crossing locate (wave owns e=wave, wave+8)
        #pragma unroll
        for (int ee = 0; ee < 2; ++ee) {
            const int e = wave + ee * 8;
            const unsigned long long m0 = segmask[e][lane];
            const unsigned long long m1 = segmask[e][64 + lane];
            const int c0 = (int)__popcll(m0), c1 = (int)__popcll(m1);
            int v0 = c0;
            #pragma unroll
            for (int d = 1; d < 64; d <<= 1) {
                int o = __shfl_up(v0, d, 64);
                if (lane >= d) v0 += o;
            }
            const int excl0 = v0 - c0;
            const int tot0  = __shfl(v0, 63, 64);
            int v1 = c1;
            #pragma unroll
            for (int d = 1; d < 64; d <<= 1) {
                int o = __shfl_up(v1, d, 64);
                if (lane >= d) v1 += o;
            }
            const int excl1 = tot0 + v1 - c1;
            pseg[e][lane]      = excl0;
            pseg[e][64 + lane] = excl1;

            int fp = 0x7FFFFFFF;
            if ((avail >> e) & 1u) {
                const int need = rem_cap[e];
                int segc = -1, kk = 0;
                if (excl0 < need && excl0 + c0 >= need)      { segc = lane;      kk = need - excl0; }
                else if (excl1 < need && excl1 + c1 >= need) { segc = 64 + lane; kk = need - excl1; }
                unsigned long long b = __ballot(segc >= 0);
                if (b) {
                    int l2    = __builtin_ctzll(b);
                    int sstar = __shfl(segc, l2, 64);
                    int k2    = __shfl(kk,   l2, 64);
                    unsigned long long m = segmask[e][sstar];
                    int rr = (int)__popcll(m & lt_mask);
                    bool hit = ((m >> lane) & 1ull) && (rr == k2 - 1);
                    unsigned long long hb = __ballot(hit);
                    fp = sstar * 64 + __builtin_ctzll(hb);
                }
            }
            if (lane == 0) fparr[e] = fp;
        }
        __syncthreads();

        // B: earliest fill event
        if (tid == 0) {
            int pm = 0x7FFFFFFF, f = 0;
            #pragma unroll
            for (int e = 0; e < N_EXP; ++e)
                if (fparr[e] < pm) { pm = fparr[e]; f = e; }
            s_pmin = pm; s_fe = f;
        }
        __syncthreads();
        const int pmin = s_pmin, fe = s_fe;
        const int segF = pmin >> 6;
        const int seglo = s_seglo;

        // C: capacity update + prune finalized bits
        if (tid < N_EXP) {
            const int e = tid;
            unsigned long long mlep = ((pmin & 63) == 63) ? ~0ull
                                      : ((1ull << ((pmin & 63) + 1)) - 1ull);
            unsigned long long m = segmask[e][segF];
            rem_cap[e] -= pseg[e][segF] + (int)__popcll(m & mlep);
            segmask[e][segF] = m & ~mlep;
        }
        for (int i = tid; i < (segF - seglo) * N_EXP; i += 512)
            segmask[i & 15][seglo + (i >> 4)] = 0ull;
        if (tid == 0) {
            evp[round] = pmin; evf[round] = fe;
            s_avail = (int)(avail & ~(1u << fe));
            s_seglo = segF;
        }
        __syncthreads();

        // D: thread-per-segment rewalk of tokens whose choice was fe
        if (round < N_EXP - 1) {
            const unsigned int navail = (unsigned int)s_avail;
            const int s = segF + tid;
            if (s < NSEG) {
                unsigned long long m = segmask[fe][s];
                if (m) {
                    segmask[fe][s] = 0ull;
                    while (m) {
                        int i = __builtin_ctzll(m); m &= m - 1ull;
                        unsigned long long pp = prefL[s * 64 + i];
                        int e2 = (int)(pp >> 60);
                        while (!((navail >> e2) & 1u)) { pp <<= 4; e2 = (int)(pp >> 60); }
                        segmask[e2][s] |= (1ull << i);   // s exclusive to this thread
                    }
                }
            }
        }
        __syncthreads();
    }

    if (tid < N_EXP) { evt[tid] = evp[tid]; evt[N_EXP + tid] = evf[tid]; }
}

// ---------------- Kernel 4: final choice per token + per-block expert counts ----------------
__global__ __launch_bounds__(256) void choice_kernel(
    const unsigned long long* __restrict__ pref, const int* __restrict__ evt,
    unsigned char* __restrict__ t2e, int* __restrict__ bcnt)
{
    __shared__ int evp[N_EXP], evf[N_EXP];
    __shared__ int sc[4][N_EXP];
    const int tid = threadIdx.x, b = blockIdx.x;
    const int wave = tid >> 6, lane = tid & 63;
    if (tid < N_EXP) evp[tid] = evt[tid];
    else if (tid < 2 * N_EXP) evf[tid - N_EXP] = evt[tid];
    __syncthreads();

    const int t = b * 256 + tid;
    unsigned int mask = 0xFFFFu;
    #pragma unroll
    for (int j = 0; j < N_EXP; ++j)
        if (evp[j] < t) mask &= ~(1u << evf[j]);

    unsigned long long pp = pref[t];
    int e = (int)(pp >> 60);
    while (!((mask >> e) & 1u)) { pp <<= 4; e = (int)(pp >> 60); }
    t2e[t] = (unsigned char)e;

    #pragma unroll
    for (int e2 = 0; e2 < N_EXP; ++e2) {
        unsigned long long mm = __ballot(e == e2);
        if (lane == e2) sc[wave][e2] = (int)__popcll(mm);
    }
    __syncthreads();
    if (tid < N_EXP)
        bcnt[b * N_EXP + tid] = sc[0][tid] + sc[1][tid] + sc[2][tid] + sc[3][tid];
}

// ---------------- Kernel 5: ranks + write out0/out1 ----------------
__global__ __launch_bounds__(256) void writeout_kernel(
    const unsigned char* __restrict__ t2e, const int* __restrict__ bcnt,
    const float* __restrict__ probs,
    float* __restrict__ out0, float* __restrict__ out1)
{
    __shared__ int base[N_EXP];
    __shared__ int sc[4][N_EXP];
    const int tid = threadIdx.x, b = blockIdx.x;
    const int wave = tid >> 6, lane = tid & 63;
    const unsigned long long lt_mask = (1ull << lane) - 1ull;

    const int t = b * 256 + tid;
    const int c = (int)t2e[t];

    unsigned long long own = 0ull;
    #pragma unroll
    for (int e2 = 0; e2 < N_EXP; ++e2) {
        unsigned long long mm = __ballot(c == e2);
        if (c == e2) own = mm;
        if (lane == e2) sc[wave][e2] = (int)__popcll(mm);
    }
    if (tid < N_EXP) {
        int s = 0;
        for (int b2 = 0; b2 < b; ++b2) s += bcnt[b2 * N_EXP + tid];
        base[tid] = s;
    }
    __syncthreads();

    int rank = (int)__popcll(own & lt_mask);
    for (int w2 = 0; w2 < wave; ++w2) rank += sc[w2][c];
    const int pos = base[c] + rank;
    out0[c * CAP + pos] = (float)t;
    out1[t] = probs[(size_t)t * N_EXP + c];
}

extern "C" void kernel_launch(void* const* d_in, const int* in_sizes, int n_in,
                              void* d_out, int out_size, void* d_ws, size_t ws_size,
                              hipStream_t stream) {
    const float* feat = (const float*)d_in[0];
    const float* W    = (const float*)d_in[1];
    const float* bias = (const float*)d_in[2];

    float* out = (float*)d_out;
    char*  ws  = (char*)d_ws;

    float* aff               = (float*)ws;
    unsigned long long* pref = (unsigned long long*)(ws + 524288);
    float* probs             = (float*)(ws + 589824);
    int* evt                 = (int*)(ws + 1114112);
    unsigned char* t2e       = (unsigned char*)(ws + 1114240);
    int* bcnt                = (int*)(ws + 1122432);

    hipLaunchKernelGGL(gemm_aff_kernel, dim3(512), dim3(256), 0, stream,
                       feat, W, aff);
    hipLaunchKernelGGL(finalize_kernel, dim3(T_TOK / 256), dim3(256), 0, stream,
                       aff, bias, pref, probs);
    hipLaunchKernelGGL(events_kernel, dim3(1), dim3(512), 0, stream,
                       pref, evt);
    hipLaunchKernelGGL(choice_kernel, dim3(T_TOK / 256), dim3(256), 0, stream,
                       pref, evt, t2e, bcnt);
    hipLaunchKernelGGL(writeout_kernel, dim3(T_TOK / 256), dim3(256), 0, stream,
                       t2e, bcnt, probs, out, out + T_TOK);
}